// Round 1
// baseline (458.347 us; speedup 1.0000x reference)
//
#include <hip/hip_runtime.h>

#define LEVEL_DIM 8

// NeuralVolume dense multi-res grid encode.
// inputs:  d_in[0] = coords  [B,3] fp32 in [0,1)
//          d_in[1] = embeddings [2396160, 8] fp32
// output:  [B, 32] fp32 (4 levels x 8 channels, level-major within a row)
__global__ __launch_bounds__(256) void nv_encode_kernel(
    const float* __restrict__ in,
    const float* __restrict__ emb,
    float* __restrict__ out,
    int B)
{
    const int b = blockIdx.x * 256 + threadIdx.x;
    if (b >= B) return;

    const float x = in[3 * b + 0];
    const float y = in[3 * b + 1];
    const float z = in[3 * b + 2];

    float* op = out + (size_t)b * 32;

    const int RES[4] = {16, 32, 64, 128};
    const int OFF[4] = {0, 4096, 36864, 299008};

    #pragma unroll
    for (int l = 0; l < 4; ++l) {
        const int R = RES[l];
        const float scale = (float)(R - 1);

        const float px = x * scale, py = y * scale, pz = z * scale;
        const float gx = floorf(px), gy = floorf(py), gz = floorf(pz);
        const float fx = px - gx, fy = py - gy, fz = pz - gz;
        const int ix = (int)gx, iy = (int)gy, iz = (int)gz;

        // reference clips every corner to [0, R-1] (no-op for x in [0,1), kept for safety)
        const int ix0 = min(max(ix, 0), R - 1);
        const int ix1 = min(max(ix + 1, 0), R - 1);
        const int iy0 = min(max(iy, 0), R - 1);
        const int iy1 = min(max(iy + 1, 0), R - 1);
        const int iz0 = min(max(iz, 0), R - 1);
        const int iz1 = min(max(iz + 1, 0), R - 1);

        const float* tbl = emb + (size_t)OFF[l] * LEVEL_DIM;
        const float wx0 = 1.0f - fx, wx1 = fx;

        float acc[8];
        #pragma unroll
        for (int c = 0; c < 8; ++c) acc[c] = 0.0f;

        // corner order matches reference CORNERS: x fastest, then y, then z
        #pragma unroll
        for (int kk = 0; kk < 2; ++kk) {
            const int   zz = kk ? iz1 : iz0;
            const float wz = kk ? fz : (1.0f - fz);
            #pragma unroll
            for (int jj = 0; jj < 2; ++jj) {
                const int   yy = jj ? iy1 : iy0;
                const float wy = jj ? fy : (1.0f - fy);

                const size_t rowbase = ((size_t)zz * R + yy) * (size_t)R;
                const float* r0 = tbl + (rowbase + ix0) * LEVEL_DIM;
                const float* r1 = tbl + (rowbase + ix1) * LEVEL_DIM;

                // weight order matches reference prod: ((wx*wy)*wz)
                const float w0 = (wx0 * wy) * wz;
                const float w1 = (wx1 * wy) * wz;

                const float4 a0 = *(const float4*)(r0);
                const float4 a1 = *(const float4*)(r0 + 4);
                const float4 b0 = *(const float4*)(r1);
                const float4 b1 = *(const float4*)(r1 + 4);

                acc[0] = fmaf(w0, a0.x, acc[0]);
                acc[1] = fmaf(w0, a0.y, acc[1]);
                acc[2] = fmaf(w0, a0.z, acc[2]);
                acc[3] = fmaf(w0, a0.w, acc[3]);
                acc[4] = fmaf(w0, a1.x, acc[4]);
                acc[5] = fmaf(w0, a1.y, acc[5]);
                acc[6] = fmaf(w0, a1.z, acc[6]);
                acc[7] = fmaf(w0, a1.w, acc[7]);

                acc[0] = fmaf(w1, b0.x, acc[0]);
                acc[1] = fmaf(w1, b0.y, acc[1]);
                acc[2] = fmaf(w1, b0.z, acc[2]);
                acc[3] = fmaf(w1, b0.w, acc[3]);
                acc[4] = fmaf(w1, b1.x, acc[4]);
                acc[5] = fmaf(w1, b1.y, acc[5]);
                acc[6] = fmaf(w1, b1.z, acc[6]);
                acc[7] = fmaf(w1, b1.w, acc[7]);
            }
        }

        *(float4*)(op + l * 8)     = make_float4(acc[0], acc[1], acc[2], acc[3]);
        *(float4*)(op + l * 8 + 4) = make_float4(acc[4], acc[5], acc[6], acc[7]);
    }
}

extern "C" void kernel_launch(void* const* d_in, const int* in_sizes, int n_in,
                              void* d_out, int out_size, void* d_ws, size_t ws_size,
                              hipStream_t stream) {
    const float* in  = (const float*)d_in[0];
    const float* emb = (const float*)d_in[1];
    float* out = (float*)d_out;

    const int B = in_sizes[0] / 3;
    const int block = 256;
    const int grid = (B + block - 1) / block;

    nv_encode_kernel<<<grid, block, 0, stream>>>(in, emb, out, B);
}